// Round 9
// baseline (182.035 us; speedup 1.0000x reference)
//
#include <hip/hip_runtime.h>
#include <hip/hip_bf16.h>

#define B_ 8
#define S_ 1024
#define D_ 1024
#define H_ 16
#define DK_ 64
#define BH_ (B_ * H_)

typedef float f32x4 __attribute__((ext_vector_type(4)));
typedef short s16x8 __attribute__((ext_vector_type(8)));
typedef short s16x4 __attribute__((ext_vector_type(4)));

// hardware transcendentals: v_exp_f32 computes 2^x, v_log_f32 computes log2(x)
#define EXP2F(x) __builtin_amdgcn_exp2f(x)
#define LOG2F(x) __builtin_amdgcn_logf(x)
#define LOG2E 1.44269504088896f

// fp32 -> bf16 (RNE), manual bit version (prep kernels)
static __device__ __forceinline__ short f2b(float f) {
  unsigned u = __builtin_bit_cast(unsigned, f);
  u = u + 0x7FFFu + ((u >> 16) & 1u);
  return (short)(u >> 16);
}
// fp32 -> bf16 via intrinsic (hot kernel; compiler fuses pairs to v_cvt_pk_bf16_f32)
static __device__ __forceinline__ short f2bn(float f) {
  __hip_bfloat16 h = __float2bfloat16(f);
  return __builtin_bit_cast(short, h);
}

static __device__ __forceinline__ int slotf(int g, int e) {
  return (e < 4) ? (4 * g + e) : (16 + 4 * g + (e - 4));
}

// ============================ PREP KERNELS =================================

// K f32 [b][s][d] -> bf16 [b][h][s][dk]
__global__ __launch_bounds__(256) void prep_k(const float* __restrict__ k,
                                              short* __restrict__ kb) {
  const int bid = blockIdx.x;  // 512
  const int s0 = (bid & 63) * 16;
  const int b = bid >> 6;
  const int tid = threadIdx.x;
#pragma unroll
  for (int it = 0; it < 8; ++it) {
    int li = it * 256 + tid;
    int s = s0 + (li >> 7);
    int ch = li & 127;
    int h = ch >> 3;
    int dk0 = (ch & 7) * 8;
    const float* src = k + ((size_t)(b * S_ + s)) * D_ + ch * 8;
    s16x8 o;
#pragma unroll
    for (int e = 0; e < 8; ++e) o[e] = f2b(src[e]);
    *(s16x8*)(kb + ((size_t)((b * H_ + h) * S_ + s)) * DK_ + dk0) = o;
  }
}

// V1/V2 f32 -> bf16 B-fragment layout [bh][jt32][db][lane][8] + column sums
__global__ __launch_bounds__(256) void prep_v(const float* __restrict__ v1,
                                              const float* __restrict__ v2,
                                              short* __restrict__ v1f,
                                              short* __restrict__ v2f,
                                              float* __restrict__ vs) {
  const int bid = blockIdx.x;  // 512
  const int sg = bid & 3;
  const int h = (bid >> 2) & 15;
  const int b = bid >> 6;
  const int tid = threadIdx.x;
  const int db = tid >> 6;
  const int lane = tid & 63;
  const int r = lane & 15;
  const int g = lane >> 4;
  const size_t inbase = (size_t)b * S_ * D_ + h * DK_ + db * 16 + r;
  float s1 = 0.f, s2 = 0.f;
#pragma unroll
  for (int it = 0; it < 8; ++it) {
    int jt = sg * 8 + it;
    int j0 = jt * 32;
    s16x8 o1, o2;
#pragma unroll
    for (int e = 0; e < 8; ++e) {
      int j = j0 + slotf(g, e);
      float a = v1[inbase + (size_t)j * D_];
      float c = v2[inbase + (size_t)j * D_];
      s1 += a;
      s2 += c;
      o1[e] = f2b(a);
      o2[e] = f2b(c);
    }
    size_t off = (((size_t)((b * H_ + h) * 32 + jt) * 4 + db) * 64 + lane) * 8;
    *(s16x8*)(v1f + off) = o1;
    *(s16x8*)(v2f + off) = o2;
  }
  s1 += __shfl_xor(s1, 16);
  s1 += __shfl_xor(s1, 32);
  s2 += __shfl_xor(s2, 16);
  s2 += __shfl_xor(s2, 32);
  if (g == 0) {
    int dd = db * 16 + r;
    atomicAdd(&vs[(size_t)b * D_ + h * DK_ + dd], s1);
    atomicAdd(&vs[(size_t)(B_ + b) * D_ + h * DK_ + dd], s2);
  }
}

// ============================ MAIN ATTENTION ================================
// 1-wave blocks, launch_bounds(64,2). Balanced heavy/light pairing per wave.
// R8 post-mortem: load-latency bound (~5000 stall cy/tile; V loaded same-
// iteration as use, L3-served). Fix: full one-iteration register prefetch of
// BOTH K and V fragments (issue 12 loads for jt+1 at loop top, compute jt
// from cur regs). +64 VGPR for V dbuf stays inside the 2-wave/SIMD budget.
__global__ __launch_bounds__(64, 2) void attn_fast5(
    const float* __restrict__ q, const short* __restrict__ kb,
    const short* __restrict__ v1f, const short* __restrict__ v2f,
    const int* __restrict__ cm, const float* __restrict__ vs,
    float* __restrict__ out) {
  const int bid = blockIdx.x;   // 4096
  const int xcd = bid & 7;
  const int idx = bid >> 3;     // 0..511
  const int unit = idx & 31;    // 32 wave-units per bh
  const int pr = unit >> 2;
  const int wpos = unit & 3;
  const int bhgrp = idx >> 5;   // 0..15
  const int bh = bhgrp * 8 + xcd;
  const int b = bh >> 4, h = bh & 15;

  const int lane = threadIdx.x & 63;
  const int r = lane & 15;
  const int g = lane >> 4;

  const int aseg = 8 + pr;                     // heavy segment
  const int bseg = 7 - pr;                     // light segment
  const int qh = aseg * 64 + wpos * 16;        // heavy col base
  const int ql = bseg * 64 + (3 - wpos) * 16;  // light col base (mirrored)
  const int iqh = qh + r;
  const int iql = ql + r;
  const int njt_h = (qh + 46) >> 5;
  const int njt_l = (ql + 46) >> 5;

  __shared__ unsigned cmw[32];
  {
    const int* cmb = cm + b * S_;
#pragma unroll
    for (int it = 0; it < 16; ++it) {
      unsigned long long m = __ballot(cmb[it * 64 + lane] == 1);
      if (lane == 0) {
        cmw[2 * it] = (unsigned)m;
        cmw[2 * it + 1] = (unsigned)(m >> 32);
      }
    }
  }
  __syncthreads();

  // Q fragments, pre-scaled by log2e/sqrt(dk) -> scores in log2 domain
  const float qscale = 0.125f * LOG2E;
  s16x8 qfh0, qfh1, qfl0, qfl1;
  {
    const float* qp = q + ((size_t)(b * S_ + qh + r)) * D_ + h * DK_;
#pragma unroll
    for (int e = 0; e < 8; ++e) qfh0[e] = f2bn(qp[8 * g + e] * qscale);
#pragma unroll
    for (int e = 0; e < 8; ++e) qfh1[e] = f2bn(qp[32 + 8 * g + e] * qscale);
    const float* qp2 = q + ((size_t)(b * S_ + ql + r)) * D_ + h * DK_;
#pragma unroll
    for (int e = 0; e < 8; ++e) qfl0[e] = f2bn(qp2[8 * g + e] * qscale);
#pragma unroll
    for (int e = 0; e < 8; ++e) qfl1[e] = f2bn(qp2[32 + 8 * g + e] * qscale);
  }

  const short* kbh = kb + (size_t)bh * S_ * DK_;
  const short* v1bh = v1f + (size_t)bh * 32 * 4 * 64 * 8;
  const short* v2bh = v2f + (size_t)bh * 32 * 4 * 64 * 8;

#define LOADK(dst0, dst1, dst2, dst3, jbase)                        \
  {                                                                 \
    const short* kr0 = kbh + (size_t)((jbase) + r) * DK_;           \
    const short* kr1 = kbh + (size_t)((jbase) + 16 + r) * DK_;      \
    dst0 = *(const s16x8*)(kr0 + 8 * g);                            \
    dst1 = *(const s16x8*)(kr0 + 32 + 8 * g);                       \
    dst2 = *(const s16x8*)(kr1 + 8 * g);                            \
    dst3 = *(const s16x8*)(kr1 + 32 + 8 * g);                       \
  }
#define LOADV(d1, d2, jtv)                                          \
  {                                                                 \
    const short* vt1 = v1bh + (size_t)(jtv) * 2048;                 \
    const short* vt2 = v2bh + (size_t)(jtv) * 2048;                 \
    _Pragma("unroll")                                               \
    for (int db = 0; db < 4; ++db) {                                \
      d1[db] = *(const s16x8*)(vt1 + (db * 64 + lane) * 8);         \
      d2[db] = *(const s16x8*)(vt2 + (db * 64 + lane) * 8);         \
    }                                                               \
  }

  // ================= pass A: Z sums (log2 domain, no max needed) ============
  float Zh = 0.f, Zl = 0.f;
  {
    s16x8 c00, c01, c10, c11;
    LOADK(c00, c01, c10, c11, 0);
    for (int jt = 0; jt < njt_h; ++jt) {
      const int jb = jt * 32;
      const bool pf = (jt + 1 < njt_h);
      s16x8 n00, n01, n10, n11;
      if (pf) LOADK(n00, n01, n10, n11, jb + 32);
      f32x4 s0 = {0.f, 0.f, 0.f, 0.f}, s1 = {0.f, 0.f, 0.f, 0.f};
      s0 = __builtin_amdgcn_mfma_f32_16x16x32_bf16(c00, qfh0, s0, 0, 0, 0);
      s0 = __builtin_amdgcn_mfma_f32_16x16x32_bf16(c01, qfh1, s0, 0, 0, 0);
      s1 = __builtin_amdgcn_mfma_f32_16x16x32_bf16(c10, qfh0, s1, 0, 0, 0);
      s1 = __builtin_amdgcn_mfma_f32_16x16x32_bf16(c11, qfh1, s1, 0, 0, 0);
      if (jt == njt_h - 1) {
#pragma unroll
        for (int e = 0; e < 4; ++e) {
          int j0 = jb + 4 * g + e, j1 = jb + 16 + 4 * g + e;
          Zh += (j0 < iqh) ? EXP2F(s0[e]) : 0.f;
          Zh += (j1 < iqh) ? EXP2F(s1[e]) : 0.f;
        }
      } else {
#pragma unroll
        for (int e = 0; e < 4; ++e) Zh += EXP2F(s0[e]) + EXP2F(s1[e]);
      }
      if (jt < njt_l) {
        f32x4 t0 = {0.f, 0.f, 0.f, 0.f}, t1 = {0.f, 0.f, 0.f, 0.f};
        t0 = __builtin_amdgcn_mfma_f32_16x16x32_bf16(c00, qfl0, t0, 0, 0, 0);
        t0 = __builtin_amdgcn_mfma_f32_16x16x32_bf16(c01, qfl1, t0, 0, 0, 0);
        t1 = __builtin_amdgcn_mfma_f32_16x16x32_bf16(c10, qfl0, t1, 0, 0, 0);
        t1 = __builtin_amdgcn_mfma_f32_16x16x32_bf16(c11, qfl1, t1, 0, 0, 0);
        if (jt == njt_l - 1) {
#pragma unroll
          for (int e = 0; e < 4; ++e) {
            int j0 = jb + 4 * g + e, j1 = jb + 16 + 4 * g + e;
            Zl += (j0 < iql) ? EXP2F(t0[e]) : 0.f;
            Zl += (j1 < iql) ? EXP2F(t1[e]) : 0.f;
          }
        } else {
#pragma unroll
          for (int e = 0; e < 4; ++e) Zl += EXP2F(t0[e]) + EXP2F(t1[e]);
        }
      }
      if (pf) { c00 = n00; c01 = n01; c10 = n10; c11 = n11; }
    }
  }
  Zh += __shfl_xor(Zh, 16);
  Zh += __shfl_xor(Zh, 32);
  Zl += __shfl_xor(Zl, 16);
  Zl += __shfl_xor(Zl, 32);
  const float lzh = -LOG2F(Zh);  // iq==0 -> Z=0 -> +inf, masked below
  const float lzl = -LOG2F(Zl);

  // ================= pass B: w = exp(p)-1, PV accumulate ====================
  f32x4 a1h[4], a2h[4], a1l[4], a2l[4];
#pragma unroll
  for (int d0 = 0; d0 < 4; ++d0) {
    a1h[d0] = (f32x4){0.f, 0.f, 0.f, 0.f};
    a2h[d0] = (f32x4){0.f, 0.f, 0.f, 0.f};
    a1l[d0] = (f32x4){0.f, 0.f, 0.f, 0.f};
    a2l[d0] = (f32x4){0.f, 0.f, 0.f, 0.f};
  }
  f32x4 wsh = {0.f, 0.f, 0.f, 0.f}, wsl = {0.f, 0.f, 0.f, 0.f};
  s16x8 ones;
#pragma unroll
  for (int e = 0; e < 8; ++e) ones[e] = (short)0x3F80;  // bf16 1.0

  {
    s16x8 c00, c01, c10, c11;     // K cur
    s16x8 vb1[4], vb2[4];         // V cur
    LOADK(c00, c01, c10, c11, 0);
    LOADV(vb1, vb2, 0);
    for (int jt = 0; jt < njt_h; ++jt) {
      const int jb = jt * 32;
      const bool pf = (jt + 1 < njt_h);
      // deep prefetch: issue ALL of next tile's loads before touching cur
      s16x8 n00, n01, n10, n11;
      s16x8 nv1[4], nv2[4];
      if (pf) {
        LOADK(n00, n01, n10, n11, jb + 32);
        LOADV(nv1, nv2, jt + 1);
      }
      f32x4 s0 = {0.f, 0.f, 0.f, 0.f}, s1 = {0.f, 0.f, 0.f, 0.f};
      s0 = __builtin_amdgcn_mfma_f32_16x16x32_bf16(c00, qfh0, s0, 0, 0, 0);
      s0 = __builtin_amdgcn_mfma_f32_16x16x32_bf16(c01, qfh1, s0, 0, 0, 0);
      s1 = __builtin_amdgcn_mfma_f32_16x16x32_bf16(c10, qfh0, s1, 0, 0, 0);
      s1 = __builtin_amdgcn_mfma_f32_16x16x32_bf16(c11, qfh1, s1, 0, 0, 0);
      const bool bc = (jt < njt_l);
      f32x4 t0, t1;
      if (bc) {
        t0 = (f32x4){0.f, 0.f, 0.f, 0.f};
        t1 = (f32x4){0.f, 0.f, 0.f, 0.f};
        t0 = __builtin_amdgcn_mfma_f32_16x16x32_bf16(c00, qfl0, t0, 0, 0, 0);
        t0 = __builtin_amdgcn_mfma_f32_16x16x32_bf16(c01, qfl1, t0, 0, 0, 0);
        t1 = __builtin_amdgcn_mfma_f32_16x16x32_bf16(c10, qfl0, t1, 0, 0, 0);
        t1 = __builtin_amdgcn_mfma_f32_16x16x32_bf16(c11, qfl1, t1, 0, 0, 0);
      }
      const unsigned cw = cmw[jt];
      int cmbit[8];
#pragma unroll
      for (int s2 = 0; s2 < 2; ++s2)
#pragma unroll
        for (int e = 0; e < 4; ++e)
          cmbit[s2 * 4 + e] = (int)((cw >> (s2 * 16 + 4 * g + e)) & 1u);
      const bool chB = (jt == njt_h - 1);
      const bool clB = (jt == njt_l - 1);
      // heavy col weights: p = 2^(s'+lz); w = e^p - 1 = 2^(p*log2e) - 1
      s16x8 wah;
      {
        float wv[8];
#pragma unroll
        for (int s2 = 0; s2 < 2; ++s2) {
          f32x4 sv = s2 ? s1 : s0;
#pragma unroll
          for (int e = 0; e < 4; ++e) {
            int j = jb + s2 * 16 + 4 * g + e;
            float pe = EXP2F(sv[e] + lzh);
            float xe = EXP2F(pe * LOG2E) - 1.f;
            bool ok = !cmbit[s2 * 4 + e];
            if (chB) ok = ok && (j < iqh);
            wv[s2 * 4 + e] = ok ? xe : 0.f;
          }
        }
#pragma unroll
        for (int e = 0; e < 8; ++e) wah[e] = f2bn(wv[e]);
      }
      s16x8 wal;
      if (bc) {
        float wv[8];
#pragma unroll
        for (int s2 = 0; s2 < 2; ++s2) {
          f32x4 sv = s2 ? t1 : t0;
#pragma unroll
          for (int e = 0; e < 4; ++e) {
            int j = jb + s2 * 16 + 4 * g + e;
            float pe = EXP2F(sv[e] + lzl);
            float xe = EXP2F(pe * LOG2E) - 1.f;
            bool ok = !cmbit[s2 * 4 + e];
            if (clB) ok = ok && (j < iql);
            wv[s2 * 4 + e] = ok ? xe : 0.f;
          }
        }
#pragma unroll
        for (int e = 0; e < 8; ++e) wal[e] = f2bn(wv[e]);
      }
      // PV + row-sum (ones-B) MFMAs
#pragma unroll
      for (int db = 0; db < 4; ++db) {
        a1h[db] = __builtin_amdgcn_mfma_f32_16x16x32_bf16(wah, vb1[db], a1h[db], 0, 0, 0);
        a2h[db] = __builtin_amdgcn_mfma_f32_16x16x32_bf16(wah, vb2[db], a2h[db], 0, 0, 0);
      }
      wsh = __builtin_amdgcn_mfma_f32_16x16x32_bf16(wah, ones, wsh, 0, 0, 0);
      if (bc) {
#pragma unroll
        for (int db = 0; db < 4; ++db) {
          a1l[db] = __builtin_amdgcn_mfma_f32_16x16x32_bf16(wal, vb1[db], a1l[db], 0, 0, 0);
          a2l[db] = __builtin_amdgcn_mfma_f32_16x16x32_bf16(wal, vb2[db], a2l[db], 0, 0, 0);
        }
        wsl = __builtin_amdgcn_mfma_f32_16x16x32_bf16(wal, ones, wsl, 0, 0, 0);
      }
      if (pf) {
        c00 = n00; c01 = n01; c10 = n10; c11 = n11;
#pragma unroll
        for (int db = 0; db < 4; ++db) {
          vb1[db] = nv1[db];
          vb2[db] = nv2[db];
        }
      }
    }
  }
#undef LOADK
#undef LOADV

  float* out1 = out;
  float* out2 = out + (size_t)B_ * S_ * D_;
  const float* vs1 = vs + (size_t)b * D_ + h * DK_;
  const float* vs2 = vs + (size_t)(B_ + b) * D_ + h * DK_;

#pragma unroll
  for (int e = 0; e < 4; ++e) {
    // heavy col (wsh[e] = row-sum for q row 4g+e; matches acc row layout)
    {
      float inv = 1.f / ((float)S_ + wsh[e]);
      int io = qh + 4 * g + e;
      size_t ro = ((size_t)(b * S_) + io) * D_ + h * DK_;
#pragma unroll
      for (int db = 0; db < 4; ++db) {
        int dd = db * 16 + r;
        out1[ro + dd] = (a1h[db][e] + vs1[dd]) * inv;
        out2[ro + dd] = (a2h[db][e] + vs2[dd]) * inv;
      }
    }
    // light col
    {
      float inv = 1.f / ((float)S_ + wsl[e]);
      int io = ql + 4 * g + e;
      bool zero = (io == 0);  // reference zeroes p row 0
      size_t ro = ((size_t)(b * S_) + io) * D_ + h * DK_;
#pragma unroll
      for (int db = 0; db < 4; ++db) {
        int dd = db * 16 + r;
        out1[ro + dd] = zero ? 0.f : (a1l[db][e] + vs1[dd]) * inv;
        out2[ro + dd] = zero ? 0.f : (a2l[db][e] + vs2[dd]) * inv;
      }
    }
  }
}

// ====================== FALLBACK (needs only 64KB ws) =======================

__global__ __launch_bounds__(256) void vsum_kernel(const float* __restrict__ v1,
                                                   const float* __restrict__ v2,
                                                   float* __restrict__ vs) {
  int bid = blockIdx.x;
  int sc = bid & 7, dc = (bid >> 3) & 3, b = bid >> 5;
  int d = dc * 256 + threadIdx.x;
  const float* p1 = v1 + ((size_t)b * S_ + sc * 128) * D_ + d;
  const float* p2 = v2 + ((size_t)b * S_ + sc * 128) * D_ + d;
  float s1 = 0.f, s2 = 0.f;
  for (int j = 0; j < 128; ++j) {
    s1 += p1[(size_t)j * D_];
    s2 += p2[(size_t)j * D_];
  }
  atomicAdd(&vs[b * D_ + d], s1);
  atomicAdd(&vs[B_ * D_ + b * D_ + d], s2);
}

__global__ __launch_bounds__(256) void dualattn_fallback(
    const float* __restrict__ q, const float* __restrict__ k,
    const float* __restrict__ v1, const float* __restrict__ v2,
    const int* __restrict__ cm, const float* __restrict__ vs,
    float* __restrict__ out) {
  const int bid = blockIdx.x;
  const int qt = bid & 15;
  const int h = (bid >> 4) & 15;
  const int b = bid >> 8;
  const int tid = threadIdx.x;
  const int wid = tid >> 6;
  const int lane = tid & 63;
  const int r = lane & 15;
  const int g = lane >> 4;
  const int qw = qt * 64 + wid * 16;
  const int iq = qw + r;

  __shared__ __align__(16) char kbuf[32 * 128];
  __shared__ __align__(16) char vtb1[64 * 64];
  __shared__ __align__(16) char vtb2[64 * 64];
  __shared__ unsigned cmw[32];

  {
    const int* cmb = cm + b * S_;
#pragma unroll
    for (int it = 0; it < 4; ++it) {
      int c = cmb[it * 256 + tid];
      unsigned long long m = __ballot(c == 1);
      if (lane == 0) {
        int w0 = (it * 256 + wid * 64) >> 5;
        cmw[w0] = (unsigned)m;
        cmw[w0 + 1] = (unsigned)(m >> 32);
      }
    }
  }

  s16x8 qf0, qf1;
  {
    const float* qp = q + ((size_t)(b * S_) + qw + r) * D_ + h * DK_;
#pragma unroll
    for (int e = 0; e < 8; ++e) qf0[e] = f2b(qp[8 * g + e] * 0.125f);
#pragma unroll
    for (int e = 0; e < 8; ++e) qf1[e] = f2b(qp[32 + 8 * g + e] * 0.125f);
  }

  const int njt = 2 * qt + 2;
  const float* kbase = k + (size_t)(b * S_) * D_ + h * DK_;
  const float* v1base = v1 + (size_t)(b * S_) * D_ + h * DK_;
  const float* v2base = v2 + (size_t)(b * S_) * D_ + h * DK_;
  const int srow = tid >> 3;
  const int sch = tid & 7;

  float m1 = -INFINITY, Z1 = 0.f;
  for (int jt = 0; jt < njt; ++jt) {
    const int jbase = jt * 32;
    __syncthreads();
    {
      const float* kr = kbase + (size_t)(jbase + srow) * D_ + sch * 8;
      s16x8 pk;
#pragma unroll
      for (int e = 0; e < 8; ++e) pk[e] = f2b(kr[e]);
      *(s16x8*)(kbuf + srow * 128 + ((sch ^ (srow & 7)) * 16)) = pk;
    }
    __syncthreads();
    if (jbase < qw + 16) {
#pragma unroll
      for (int sub = 0; sub < 2; ++sub) {
        const int jsb = jbase + sub * 16;
        if (jsb < qw + 16) {
          const int row = sub * 16 + r;
          s16x8 ka0 = *(const s16x8*)(kbuf + row * 128 + ((g ^ (row & 7)) * 16));
          s16x8 ka1 = *(const s16x8*)(kbuf + row * 128 + (((4 + g) ^ (row & 7)) * 16));
          f32x4 sv = {0.f, 0.f, 0.f, 0.f};
          sv = __builtin_amdgcn_mfma_f32_16x16x32_bf16(ka0, qf0, sv, 0, 0, 0);
          sv = __builtin_amdgcn_mfma_f32_16x16x32_bf16(ka1, qf1, sv, 0, 0, 0);
          float tm = m1;
#pragma unroll
          for (int e = 0; e < 4; ++e) {
            int j = jsb + 4 * g + e;
            if (j < iq) tm = fmaxf(tm, sv[e]);
          }
          if (tm > m1) { Z1 *= __expf(m1 - tm); m1 = tm; }
#pragma unroll
          for (int e = 0; e < 4; ++e) {
            int j = jsb + 4 * g + e;
            if (j < iq) Z1 += __expf(sv[e] - tm);
          }
        }
      }
    }
  }
#pragma unroll
  for (int off = 16; off < 64; off <<= 1) {
    float mo = __shfl_xor(m1, off);
    float zo = __shfl_xor(Z1, off);
    float mn = fmaxf(m1, mo);
    if (mn > -INFINITY) {
      Z1 = Z1 * __expf(m1 - mn) + zo * __expf(mo - mn);
      m1 = mn;
    }
  }
  float z1i;
  if (m1 > -INFINITY) { z1i = 1.f / Z1; }
  else { z1i = 0.f; m1 = 0.f; }

  f32x4 acc1[4], acc2[4];
#pragma unroll
  for (int d0 = 0; d0 < 4; ++d0) {
    acc1[d0] = (f32x4){0.f, 0.f, 0.f, 0.f};
    acc2[d0] = (f32x4){0.f, 0.f, 0.f, 0.f};
  }
  float wsum = 0.f;

  for (int jt = 0; jt < njt; ++jt) {
    const int jbase = jt * 32;
    __syncthreads();
    {
      const float* kr = kbase + (size_t)(jbase + srow) * D_ + sch * 8;
      s16x8 pk;
#pragma unroll
      for (int e = 0; e < 8; ++e) pk[e] = f2b(kr[e]);
      *(s16x8*)(kbuf + srow * 128 + ((sch ^ (srow & 7)) * 16)) = pk;
      const float* v1r = v1base + (size_t)(jbase + srow) * D_ + sch * 8;
      const float* v2r = v2base + (size_t)(jbase + srow) * D_ + sch * 8;
#pragma unroll
      for (int e = 0; e < 8; ++e) {
        int dd = sch * 8 + e;
        int off = dd * 64 + (((srow >> 2) ^ (dd & 7)) * 8) + (srow & 3) * 2;
        *(short*)(vtb1 + off) = f2b(v1r[e]);
        *(short*)(vtb2 + off) = f2b(v2r[e]);
      }
    }
    __syncthreads();
    if (jbase < qw + 16) {
      const unsigned cmword = cmw[jbase >> 5];
      float w[8];
#pragma unroll
      for (int sub = 0; sub < 2; ++sub) {
        const int jsb = jbase + sub * 16;
        if (jsb < qw + 16) {
          const int row = sub * 16 + r;
          s16x8 ka0 = *(const s16x8*)(kbuf + row * 128 + ((g ^ (row & 7)) * 16));
          s16x8 ka1 = *(const s16x8*)(kbuf + row * 128 + (((4 + g) ^ (row & 7)) * 16));
          f32x4 sv = {0.f, 0.f, 0.f, 0.f};
          sv = __builtin_amdgcn_mfma_f32_16x16x32_bf16(ka0, qf0, sv, 0, 0, 0);
          sv = __builtin_amdgcn_mfma_f32_16x16x32_bf16(ka1, qf1, sv, 0, 0, 0);
#pragma unroll
          for (int e = 0; e < 4; ++e) {
            int j = jsb + 4 * g + e;
            float x = 0.f;
            if (j < iq && !((cmword >> (j & 31)) & 1u)) {
              float p = __expf(sv[e] - m1) * z1i;
              x = __expf(p) - 1.f;
            }
            w[sub * 4 + e] = x;
            wsum += x;
          }
        } else {
#pragma unroll
          for (int e = 0; e < 4; ++e) w[sub * 4 + e] = 0.f;
        }
      }
      s16x8 wa;
#pragma unroll
      for (int e = 0; e < 8; ++e) wa[e] = f2b(w[e]);
#pragma unroll
      for (int db = 0; db < 4; ++db) {
        const int dd = db * 16 + r;
        const int off0 = dd * 64 + ((g ^ (dd & 7)) * 8);
        const int off1 = dd * 64 + (((4 + g) ^ (dd & 7)) * 8);
        s16x4 lo1 = *(const s16x4*)(vtb1 + off0);
        s16x4 hi1 = *(const s16x4*)(vtb1 + off1);
        s16x8 vb1 = __builtin_shufflevector(lo1, hi1, 0, 1, 2, 3, 4, 5, 6, 7);
        acc1[db] = __builtin_amdgcn_mfma_f32_16x16x32_bf16(wa, vb1, acc1[db], 0, 0, 0);
        s16x4 lo2 = *(const s16x4*)(vtb2 + off0);
        s16x4 hi2 = *(const s16x4*)(vtb2 + off1);
        s16x8 vb2 = __builtin_shufflevector(lo2, hi2, 0, 1, 2, 3, 4, 5, 6, 7);
        acc2[db] = __builtin_amdgcn_mfma_f32_16x16x32_bf16(wa, vb2, acc2[db], 0, 0, 0);
      }
    }
  }

  wsum += __shfl_xor(wsum, 16);
  wsum += __shfl_xor(wsum, 32);
  const float z2 = (float)S_ + wsum;

  float* out1 = out;
  float* out2 = out + (size_t)B_ * S_ * D_;
#pragma unroll
  for (int e = 0; e < 4; ++e) {
    float z2e = __shfl(z2, 4 * g + e);
    float inv = 1.f / z2e;
    int io = qw + 4 * g + e;
    bool zero = (io == 0);
    size_t ro = ((size_t)(b * S_) + io) * D_ + h * DK_;
#pragma unroll
    for (int db = 0; db < 4; ++db) {
      int dd = db * 16 + r;
      float c1 = vs[(size_t)b * D_ + h * DK_ + dd];
      float c2 = vs[(size_t)(B_ + b) * D_ + h * DK_ + dd];
      out1[ro + dd] = zero ? 0.f : (acc1[db][e] + c1) * inv;
      out2[ro + dd] = zero ? 0.f : (acc2[db][e] + c2) * inv;
    }
  }
}

// ============================================================================

extern "C" void kernel_launch(void* const* d_in, const int* in_sizes, int n_in,
                              void* d_out, int out_size, void* d_ws, size_t ws_size,
                              hipStream_t stream) {
  (void)in_sizes; (void)n_in; (void)out_size;
  const float* q = (const float*)d_in[0];
  const float* k = (const float*)d_in[1];
  const float* v1 = (const float*)d_in[2];
  const float* v2 = (const float*)d_in[3];
  const int* cm = (const int*)d_in[4];
  float* outp = (float*)d_out;

  const size_t VS_BYTES = 2 * B_ * D_ * sizeof(float);  // 64 KB
  const size_t FRAG_SHORTS = (size_t)BH_ * S_ * DK_;    // 8M shorts
  const size_t FRAG_BYTES = FRAG_SHORTS * 2;            // 16 MB
  const size_t NEED = VS_BYTES + 3 * FRAG_BYTES;

  float* vs = (float*)d_ws;
  (void)hipMemsetAsync(vs, 0, VS_BYTES, stream);

  if (ws_size >= NEED) {
    short* kb = (short*)((char*)d_ws + VS_BYTES);
    short* v1f = kb + FRAG_SHORTS;
    short* v2f = v1f + FRAG_SHORTS;
    prep_k<<<B_ * (S_ / 16), 256, 0, stream>>>(k, kb);
    prep_v<<<B_ * H_ * 4, 256, 0, stream>>>(v1, v2, v1f, v2f, vs);
    attn_fast5<<<4096, 64, 0, stream>>>(q, kb, v1f, v2f, cm, vs, outp);
  } else {
    vsum_kernel<<<256, 256, 0, stream>>>(v1, v2, vs);
    dualattn_fallback<<<B_ * H_ * 16, 256, 0, stream>>>(q, k, v1, v2, cm, vs, outp);
  }
}

// Round 10
// 117.828 us; speedup vs baseline: 1.5449x; 1.5449x over previous
//
#include <hip/hip_runtime.h>
#include <hip/hip_bf16.h>

#define B_ 8
#define S_ 1024
#define D_ 1024
#define H_ 16
#define DK_ 64
#define BH_ (B_ * H_)

typedef float f32x4 __attribute__((ext_vector_type(4)));
typedef short s16x8 __attribute__((ext_vector_type(8)));
typedef short s16x4 __attribute__((ext_vector_type(4)));

// hardware transcendentals: v_exp_f32 computes 2^x, v_log_f32 computes log2(x)
#define EXP2F(x) __builtin_amdgcn_exp2f(x)
#define LOG2F(x) __builtin_amdgcn_logf(x)
#define LOG2E 1.44269504088896f

// fp32 -> bf16 (RNE), manual bit version (prep kernels)
static __device__ __forceinline__ short f2b(float f) {
  unsigned u = __builtin_bit_cast(unsigned, f);
  u = u + 0x7FFFu + ((u >> 16) & 1u);
  return (short)(u >> 16);
}
// fp32 -> bf16 via intrinsic
static __device__ __forceinline__ short f2bn(float f) {
  __hip_bfloat16 h = __float2bfloat16(f);
  return __builtin_bit_cast(short, h);
}

static __device__ __forceinline__ int slotf(int g, int e) {
  return (e < 4) ? (4 * g + e) : (16 + 4 * g + (e - 4));
}

// ============================ PREP KERNELS =================================

// K f32 [b][s][d] -> bf16 [b][h][s][dk]
__global__ __launch_bounds__(256) void prep_k(const float* __restrict__ k,
                                              short* __restrict__ kb) {
  const int bid = blockIdx.x;  // 512
  const int s0 = (bid & 63) * 16;
  const int b = bid >> 6;
  const int tid = threadIdx.x;
#pragma unroll
  for (int it = 0; it < 8; ++it) {
    int li = it * 256 + tid;
    int s = s0 + (li >> 7);
    int ch = li & 127;
    int h = ch >> 3;
    int dk0 = (ch & 7) * 8;
    const float* src = k + ((size_t)(b * S_ + s)) * D_ + ch * 8;
    s16x8 o;
#pragma unroll
    for (int e = 0; e < 8; ++e) o[e] = f2b(src[e]);
    *(s16x8*)(kb + ((size_t)((b * H_ + h) * S_ + s)) * DK_ + dk0) = o;
  }
}

// V1/V2 f32 -> bf16 B-fragment layout [bh][jt32][db][lane][8] + column sums
__global__ __launch_bounds__(256) void prep_v(const float* __restrict__ v1,
                                              const float* __restrict__ v2,
                                              short* __restrict__ v1f,
                                              short* __restrict__ v2f,
                                              float* __restrict__ vs) {
  const int bid = blockIdx.x;  // 512
  const int sg = bid & 3;
  const int h = (bid >> 2) & 15;
  const int b = bid >> 6;
  const int tid = threadIdx.x;
  const int db = tid >> 6;
  const int lane = tid & 63;
  const int r = lane & 15;
  const int g = lane >> 4;
  const size_t inbase = (size_t)b * S_ * D_ + h * DK_ + db * 16 + r;
  float s1 = 0.f, s2 = 0.f;
#pragma unroll
  for (int it = 0; it < 8; ++it) {
    int jt = sg * 8 + it;
    int j0 = jt * 32;
    s16x8 o1, o2;
#pragma unroll
    for (int e = 0; e < 8; ++e) {
      int j = j0 + slotf(g, e);
      float a = v1[inbase + (size_t)j * D_];
      float c = v2[inbase + (size_t)j * D_];
      s1 += a;
      s2 += c;
      o1[e] = f2b(a);
      o2[e] = f2b(c);
    }
    size_t off = (((size_t)((b * H_ + h) * 32 + jt) * 4 + db) * 64 + lane) * 8;
    *(s16x8*)(v1f + off) = o1;
    *(s16x8*)(v2f + off) = o2;
  }
  s1 += __shfl_xor(s1, 16);
  s1 += __shfl_xor(s1, 32);
  s2 += __shfl_xor(s2, 16);
  s2 += __shfl_xor(s2, 32);
  if (g == 0) {
    int dd = db * 16 + r;
    atomicAdd(&vs[(size_t)b * D_ + h * DK_ + dd], s1);
    atomicAdd(&vs[(size_t)(B_ + b) * D_ + h * DK_ + dd], s2);
  }
}

// ============================ MAIN ATTENTION ================================
// R9 post-mortem: R5/R8/R9 all 165us with identical per-wave-private K/V
// fragment traffic (~1.6 GB, ~9.7 TB/s) -> L2/L3-gather-bound. Fix: 4 waves
// of a 256-thread block SHARE K/V tiles via LDS (T14 staging: issue loads for
// jt+1 early, ds_write late, 1 barrier/tile, double buffer). Traffic /4.
// Heavy seg (8+pr, 64 rows) + mirror light seg (7-pr) per block; per-wave
// 16 heavy + 16 light rows (wid mirrored). Causal/cm masks uniform per tile.
__global__ __launch_bounds__(256, 2) void attn_fast6(
    const float* __restrict__ q, const short* __restrict__ kb,
    const short* __restrict__ v1f, const short* __restrict__ v2f,
    const int* __restrict__ cm, const float* __restrict__ vs,
    float* __restrict__ out) {
  const int bid = blockIdx.x;   // 1024
  const int xcd = bid & 7;
  const int idx = bid >> 3;     // 0..127
  const int pr = idx & 7;
  const int bhgrp = idx >> 3;   // 0..15
  const int bh = bhgrp * 8 + xcd;
  const int b = bh >> 4, h = bh & 15;

  const int tid = threadIdx.x;
  const int wid = tid >> 6;
  const int lane = tid & 63;
  const int r = lane & 15;
  const int g = lane >> 4;

  const int aseg = 8 + pr;                    // heavy segment (64 rows)
  const int bseg = 7 - pr;                    // light segment
  const int qh = aseg * 64 + wid * 16;        // this wave's heavy col base
  const int ql = bseg * 64 + (3 - wid) * 16;  // light col base (mirrored)
  const int iqh = qh + r;
  const int iql = ql + r;
  const int njt = (aseg * 64 + 94) >> 5;      // block-uniform tile count

  // LDS: 2 buffers x {K 4KB (swizzled) | V1 4KB | V2 4KB}
  __shared__ __align__(16) char sbuf[2][12288];
  __shared__ unsigned cmw[32];
  {
    const int* cmb = cm + b * S_;
#pragma unroll
    for (int it = 0; it < 4; ++it) {
      unsigned long long m = __ballot(cmb[it * 256 + tid] == 1);
      if (lane == 0) {
        int w0 = it * 8 + wid * 2;
        cmw[w0] = (unsigned)m;
        cmw[w0 + 1] = (unsigned)(m >> 32);
      }
    }
  }

  // Q fragments, pre-scaled by log2e/sqrt(dk) -> scores in log2 domain
  const float qscale = 0.125f * LOG2E;
  s16x8 qfh0, qfh1, qfl0, qfl1;
  {
    const float* qp = q + ((size_t)(b * S_ + qh + r)) * D_ + h * DK_;
#pragma unroll
    for (int e = 0; e < 8; ++e) qfh0[e] = f2bn(qp[8 * g + e] * qscale);
#pragma unroll
    for (int e = 0; e < 8; ++e) qfh1[e] = f2bn(qp[32 + 8 * g + e] * qscale);
    const float* qp2 = q + ((size_t)(b * S_ + ql + r)) * D_ + h * DK_;
#pragma unroll
    for (int e = 0; e < 8; ++e) qfl0[e] = f2bn(qp2[8 * g + e] * qscale);
#pragma unroll
    for (int e = 0; e < 8; ++e) qfl1[e] = f2bn(qp2[32 + 8 * g + e] * qscale);
  }

  const short* kbh = kb + (size_t)bh * S_ * DK_;            // 2048 shorts/tile
  const short* v1bh = v1f + (size_t)bh * 32 * 2048;
  const short* v2bh = v2f + (size_t)bh * 32 * 2048;

  const int srow = tid >> 3;  // staging K row 0..31
  const int sch = tid & 7;    // staging K chunk 0..7

// staging: thread t moves 16B chunk t of the 4KB tile
#define SLK(reg, jtv) reg = *(const s16x8*)(kbh + (size_t)(jtv)*2048 + tid * 8);
#define SLV(d1, d2, jtv)                                           \
  {                                                                \
    d1 = *(const s16x8*)(v1bh + (size_t)(jtv)*2048 + tid * 8);     \
    d2 = *(const s16x8*)(v2bh + (size_t)(jtv)*2048 + tid * 8);     \
  }
#define SWK(buf, reg) \
  *(s16x8*)((buf) + srow * 128 + ((sch ^ (srow & 7)) * 16)) = reg;
#define SWV(buf, d1, d2)                        \
  {                                             \
    *(s16x8*)((buf) + 4096 + tid * 16) = d1;    \
    *(s16x8*)((buf) + 8192 + tid * 16) = d2;    \
  }
// fragment read from swizzled K tile
#define KFRAG(sK, row, quad) \
  (*(const s16x8*)((sK) + (row)*128 + (((quad) ^ ((row)&7)) * 16)))

  // ================= pass A: Z sums (log2 domain) ===========================
  float Zh = 0.f, Zl = 0.f;
  {
    s16x8 rk;
    SLK(rk, 0);
    __syncthreads();  // cmw ready; buffers free
    SWK(sbuf[0], rk);
    __syncthreads();
    for (int jt = 0; jt < njt; ++jt) {
      const int jb = jt * 32;
      const char* sK = sbuf[jt & 1];
      const bool pf = (jt + 1 < njt);
      s16x8 rk2;
      if (pf) SLK(rk2, jt + 1);
      s16x8 k00 = KFRAG(sK, r, g);
      s16x8 k01 = KFRAG(sK, r, 4 + g);
      s16x8 k10 = KFRAG(sK, 16 + r, g);
      s16x8 k11 = KFRAG(sK, 16 + r, 4 + g);
      f32x4 s0 = {0.f, 0.f, 0.f, 0.f}, s1 = {0.f, 0.f, 0.f, 0.f};
      s0 = __builtin_amdgcn_mfma_f32_16x16x32_bf16(k00, qfh0, s0, 0, 0, 0);
      s0 = __builtin_amdgcn_mfma_f32_16x16x32_bf16(k01, qfh1, s0, 0, 0, 0);
      s1 = __builtin_amdgcn_mfma_f32_16x16x32_bf16(k10, qfh0, s1, 0, 0, 0);
      s1 = __builtin_amdgcn_mfma_f32_16x16x32_bf16(k11, qfh1, s1, 0, 0, 0);
#pragma unroll
      for (int e = 0; e < 4; ++e) {
        int j0 = jb + 4 * g + e, j1 = jb + 16 + 4 * g + e;
        Zh += (j0 < iqh) ? EXP2F(s0[e]) : 0.f;
        Zh += (j1 < iqh) ? EXP2F(s1[e]) : 0.f;
      }
      if (jb < ql + 16) {
        f32x4 t0 = {0.f, 0.f, 0.f, 0.f}, t1 = {0.f, 0.f, 0.f, 0.f};
        t0 = __builtin_amdgcn_mfma_f32_16x16x32_bf16(k00, qfl0, t0, 0, 0, 0);
        t0 = __builtin_amdgcn_mfma_f32_16x16x32_bf16(k01, qfl1, t0, 0, 0, 0);
        t1 = __builtin_amdgcn_mfma_f32_16x16x32_bf16(k10, qfl0, t1, 0, 0, 0);
        t1 = __builtin_amdgcn_mfma_f32_16x16x32_bf16(k11, qfl1, t1, 0, 0, 0);
#pragma unroll
        for (int e = 0; e < 4; ++e) {
          int j0 = jb + 4 * g + e, j1 = jb + 16 + 4 * g + e;
          Zl += (j0 < iql) ? EXP2F(t0[e]) : 0.f;
          Zl += (j1 < iql) ? EXP2F(t1[e]) : 0.f;
        }
      }
      if (pf) SWK(sbuf[(jt + 1) & 1], rk2);
      __syncthreads();
    }
  }
  Zh += __shfl_xor(Zh, 16);
  Zh += __shfl_xor(Zh, 32);
  Zl += __shfl_xor(Zl, 16);
  Zl += __shfl_xor(Zl, 32);
  const float lzh = -LOG2F(Zh);  // iq==0 -> Z=0 -> +inf, masked below
  const float lzl = -LOG2F(Zl);

  // ================= pass B: w = exp(p)-1, PV accumulate ====================
  f32x4 a1h[4], a2h[4], a1l[4], a2l[4];
#pragma unroll
  for (int d0 = 0; d0 < 4; ++d0) {
    a1h[d0] = (f32x4){0.f, 0.f, 0.f, 0.f};
    a2h[d0] = (f32x4){0.f, 0.f, 0.f, 0.f};
    a1l[d0] = (f32x4){0.f, 0.f, 0.f, 0.f};
    a2l[d0] = (f32x4){0.f, 0.f, 0.f, 0.f};
  }
  f32x4 wsh = {0.f, 0.f, 0.f, 0.f}, wsl = {0.f, 0.f, 0.f, 0.f};
  s16x8 ones;
#pragma unroll
  for (int e = 0; e < 8; ++e) ones[e] = (short)0x3F80;  // bf16 1.0

  {
    s16x8 rk, rv1, rv2;
    SLK(rk, 0);
    SLV(rv1, rv2, 0);
    SWK(sbuf[0], rk);
    SWV(sbuf[0], rv1, rv2);
    __syncthreads();
    for (int jt = 0; jt < njt; ++jt) {
      const int jb = jt * 32;
      const char* sB = sbuf[jt & 1];
      const bool pf = (jt + 1 < njt);
      s16x8 rk2, rv12, rv22;
      if (pf) {
        SLK(rk2, jt + 1);
        SLV(rv12, rv22, jt + 1);
      }
      s16x8 k00 = KFRAG(sB, r, g);
      s16x8 k01 = KFRAG(sB, r, 4 + g);
      s16x8 k10 = KFRAG(sB, 16 + r, g);
      s16x8 k11 = KFRAG(sB, 16 + r, 4 + g);
      f32x4 s0 = {0.f, 0.f, 0.f, 0.f}, s1 = {0.f, 0.f, 0.f, 0.f};
      s0 = __builtin_amdgcn_mfma_f32_16x16x32_bf16(k00, qfh0, s0, 0, 0, 0);
      s0 = __builtin_amdgcn_mfma_f32_16x16x32_bf16(k01, qfh1, s0, 0, 0, 0);
      s1 = __builtin_amdgcn_mfma_f32_16x16x32_bf16(k10, qfh0, s1, 0, 0, 0);
      s1 = __builtin_amdgcn_mfma_f32_16x16x32_bf16(k11, qfh1, s1, 0, 0, 0);
      const bool bc = (jb < ql + 16);
      f32x4 t0, t1;
      if (bc) {
        t0 = (f32x4){0.f, 0.f, 0.f, 0.f};
        t1 = (f32x4){0.f, 0.f, 0.f, 0.f};
        t0 = __builtin_amdgcn_mfma_f32_16x16x32_bf16(k00, qfl0, t0, 0, 0, 0);
        t0 = __builtin_amdgcn_mfma_f32_16x16x32_bf16(k01, qfl1, t0, 0, 0, 0);
        t1 = __builtin_amdgcn_mfma_f32_16x16x32_bf16(k10, qfl0, t1, 0, 0, 0);
        t1 = __builtin_amdgcn_mfma_f32_16x16x32_bf16(k11, qfl1, t1, 0, 0, 0);
      }
      // V fragments from LDS (linear, conflict-free)
      s16x8 vb1[4], vb2[4];
#pragma unroll
      for (int db = 0; db < 4; ++db) {
        vb1[db] = *(const s16x8*)(sB + 4096 + (db * 64 + lane) * 16);
        vb2[db] = *(const s16x8*)(sB + 8192 + (db * 64 + lane) * 16);
      }
      const unsigned cw = cmw[jt];
      int cmbit[8];
#pragma unroll
      for (int s2 = 0; s2 < 2; ++s2)
#pragma unroll
        for (int e = 0; e < 4; ++e)
          cmbit[s2 * 4 + e] = (int)((cw >> (s2 * 16 + 4 * g + e)) & 1u);
      // heavy weights: p = 2^(s'+lz); w = e^p-1 = 2^(p*log2e)-1; mask every tile
      s16x8 wah;
      {
        float wv[8];
#pragma unroll
        for (int s2 = 0; s2 < 2; ++s2) {
          f32x4 sv = s2 ? s1 : s0;
#pragma unroll
          for (int e = 0; e < 4; ++e) {
            int j = jb + s2 * 16 + 4 * g + e;
            float pe = EXP2F(sv[e] + lzh);
            float xe = EXP2F(pe * LOG2E) - 1.f;
            bool ok = !cmbit[s2 * 4 + e] && (j < iqh);
            wv[s2 * 4 + e] = ok ? xe : 0.f;
          }
        }
#pragma unroll
        for (int e = 0; e < 8; ++e) wah[e] = f2bn(wv[e]);
      }
      s16x8 wal;
      if (bc) {
        float wv[8];
#pragma unroll
        for (int s2 = 0; s2 < 2; ++s2) {
          f32x4 sv = s2 ? t1 : t0;
#pragma unroll
          for (int e = 0; e < 4; ++e) {
            int j = jb + s2 * 16 + 4 * g + e;
            float pe = EXP2F(sv[e] + lzl);
            float xe = EXP2F(pe * LOG2E) - 1.f;
            bool ok = !cmbit[s2 * 4 + e] && (j < iql);
            wv[s2 * 4 + e] = ok ? xe : 0.f;
          }
        }
#pragma unroll
        for (int e = 0; e < 8; ++e) wal[e] = f2bn(wv[e]);
      }
      // PV + row-sum (ones-B) MFMAs
#pragma unroll
      for (int db = 0; db < 4; ++db) {
        a1h[db] = __builtin_amdgcn_mfma_f32_16x16x32_bf16(wah, vb1[db], a1h[db], 0, 0, 0);
        a2h[db] = __builtin_amdgcn_mfma_f32_16x16x32_bf16(wah, vb2[db], a2h[db], 0, 0, 0);
      }
      wsh = __builtin_amdgcn_mfma_f32_16x16x32_bf16(wah, ones, wsh, 0, 0, 0);
      if (bc) {
#pragma unroll
        for (int db = 0; db < 4; ++db) {
          a1l[db] = __builtin_amdgcn_mfma_f32_16x16x32_bf16(wal, vb1[db], a1l[db], 0, 0, 0);
          a2l[db] = __builtin_amdgcn_mfma_f32_16x16x32_bf16(wal, vb2[db], a2l[db], 0, 0, 0);
        }
        wsl = __builtin_amdgcn_mfma_f32_16x16x32_bf16(wal, ones, wsl, 0, 0, 0);
      }
      if (pf) {
        SWK(sbuf[(jt + 1) & 1], rk2);
        SWV(sbuf[(jt + 1) & 1], rv12, rv22);
      }
      __syncthreads();
    }
  }
#undef SLK
#undef SLV
#undef SWK
#undef SWV
#undef KFRAG

  float* out1 = out;
  float* out2 = out + (size_t)B_ * S_ * D_;
  const float* vs1 = vs + (size_t)b * D_ + h * DK_;
  const float* vs2 = vs + (size_t)(B_ + b) * D_ + h * DK_;

#pragma unroll
  for (int e = 0; e < 4; ++e) {
    // heavy col (wsh[e] = row-sum for q row 4g+e; matches acc row layout)
    {
      float inv = 1.f / ((float)S_ + wsh[e]);
      int io = qh + 4 * g + e;
      size_t ro = ((size_t)(b * S_) + io) * D_ + h * DK_;
#pragma unroll
      for (int db = 0; db < 4; ++db) {
        int dd = db * 16 + r;
        out1[ro + dd] = (a1h[db][e] + vs1[dd]) * inv;
        out2[ro + dd] = (a2h[db][e] + vs2[dd]) * inv;
      }
    }
    // light col
    {
      float inv = 1.f / ((float)S_ + wsl[e]);
      int io = ql + 4 * g + e;
      bool zero = (io == 0);  // reference zeroes p row 0
      size_t ro = ((size_t)(b * S_) + io) * D_ + h * DK_;
#pragma unroll
      for (int db = 0; db < 4; ++db) {
        int dd = db * 16 + r;
        out1[ro + dd] = zero ? 0.f : (a1l[db][e] + vs1[dd]) * inv;
        out2[ro + dd] = zero ? 0.f : (a2l[db][e] + vs2[dd]) * inv;
      }
    }
  }
}

// ====================== FALLBACK (needs only 64KB ws) =======================

__global__ __launch_bounds__(256) void vsum_kernel(const float* __restrict__ v1,
                                                   const float* __restrict__ v2,
                                                   float* __restrict__ vs) {
  int bid = blockIdx.x;
  int sc = bid & 7, dc = (bid >> 3) & 3, b = bid >> 5;
  int d = dc * 256 + threadIdx.x;
  const float* p1 = v1 + ((size_t)b * S_ + sc * 128) * D_ + d;
  const float* p2 = v2 + ((size_t)b * S_ + sc * 128) * D_ + d;
  float s1 = 0.f, s2 = 0.f;
  for (int j = 0; j < 128; ++j) {
    s1 += p1[(size_t)j * D_];
    s2 += p2[(size_t)j * D_];
  }
  atomicAdd(&vs[b * D_ + d], s1);
  atomicAdd(&vs[B_ * D_ + b * D_ + d], s2);
}

__global__ __launch_bounds__(256) void dualattn_fallback(
    const float* __restrict__ q, const float* __restrict__ k,
    const float* __restrict__ v1, const float* __restrict__ v2,
    const int* __restrict__ cm, const float* __restrict__ vs,
    float* __restrict__ out) {
  const int bid = blockIdx.x;
  const int qt = bid & 15;
  const int h = (bid >> 4) & 15;
  const int b = bid >> 8;
  const int tid = threadIdx.x;
  const int wid = tid >> 6;
  const int lane = tid & 63;
  const int r = lane & 15;
  const int g = lane >> 4;
  const int qw = qt * 64 + wid * 16;
  const int iq = qw + r;

  __shared__ __align__(16) char kbuf[32 * 128];
  __shared__ __align__(16) char vtb1[64 * 64];
  __shared__ __align__(16) char vtb2[64 * 64];
  __shared__ unsigned cmw[32];

  {
    const int* cmb = cm + b * S_;
#pragma unroll
    for (int it = 0; it < 4; ++it) {
      int c = cmb[it * 256 + tid];
      unsigned long long m = __ballot(c == 1);
      if (lane == 0) {
        int w0 = (it * 256 + wid * 64) >> 5;
        cmw[w0] = (unsigned)m;
        cmw[w0 + 1] = (unsigned)(m >> 32);
      }
    }
  }

  s16x8 qf0, qf1;
  {
    const float* qp = q + ((size_t)(b * S_) + qw + r) * D_ + h * DK_;
#pragma unroll
    for (int e = 0; e < 8; ++e) qf0[e] = f2b(qp[8 * g + e] * 0.125f);
#pragma unroll
    for (int e = 0; e < 8; ++e) qf1[e] = f2b(qp[32 + 8 * g + e] * 0.125f);
  }

  const int njt = 2 * qt + 2;
  const float* kbase = k + (size_t)(b * S_) * D_ + h * DK_;
  const float* v1base = v1 + (size_t)(b * S_) * D_ + h * DK_;
  const float* v2base = v2 + (size_t)(b * S_) * D_ + h * DK_;
  const int srow = tid >> 3;
  const int sch = tid & 7;

  float m1 = -INFINITY, Z1 = 0.f;
  for (int jt = 0; jt < njt; ++jt) {
    const int jbase = jt * 32;
    __syncthreads();
    {
      const float* kr = kbase + (size_t)(jbase + srow) * D_ + sch * 8;
      s16x8 pk;
#pragma unroll
      for (int e = 0; e < 8; ++e) pk[e] = f2b(kr[e]);
      *(s16x8*)(kbuf + srow * 128 + ((sch ^ (srow & 7)) * 16)) = pk;
    }
    __syncthreads();
    if (jbase < qw + 16) {
#pragma unroll
      for (int sub = 0; sub < 2; ++sub) {
        const int jsb = jbase + sub * 16;
        if (jsb < qw + 16) {
          const int row = sub * 16 + r;
          s16x8 ka0 = *(const s16x8*)(kbuf + row * 128 + ((g ^ (row & 7)) * 16));
          s16x8 ka1 = *(const s16x8*)(kbuf + row * 128 + (((4 + g) ^ (row & 7)) * 16));
          f32x4 sv = {0.f, 0.f, 0.f, 0.f};
          sv = __builtin_amdgcn_mfma_f32_16x16x32_bf16(ka0, qf0, sv, 0, 0, 0);
          sv = __builtin_amdgcn_mfma_f32_16x16x32_bf16(ka1, qf1, sv, 0, 0, 0);
          float tm = m1;
#pragma unroll
          for (int e = 0; e < 4; ++e) {
            int j = jsb + 4 * g + e;
            if (j < iq) tm = fmaxf(tm, sv[e]);
          }
          if (tm > m1) { Z1 *= __expf(m1 - tm); m1 = tm; }
#pragma unroll
          for (int e = 0; e < 4; ++e) {
            int j = jsb + 4 * g + e;
            if (j < iq) Z1 += __expf(sv[e] - tm);
          }
        }
      }
    }
  }
#pragma unroll
  for (int off = 16; off < 64; off <<= 1) {
    float mo = __shfl_xor(m1, off);
    float zo = __shfl_xor(Z1, off);
    float mn = fmaxf(m1, mo);
    if (mn > -INFINITY) {
      Z1 = Z1 * __expf(m1 - mn) + zo * __expf(mo - mn);
      m1 = mn;
    }
  }
  float z1i;
  if (m1 > -INFINITY) { z1i = 1.f / Z1; }
  else { z1i = 0.f; m1 = 0.f; }

  f32x4 acc1[4], acc2[4];
#pragma unroll
  for (int d0 = 0; d0 < 4; ++d0) {
    acc1[d0] = (f32x4){0.f, 0.f, 0.f, 0.f};
    acc2[d0] = (f32x4){0.f, 0.f, 0.f, 0.f};
  }
  float wsum = 0.f;

  for (int jt = 0; jt < njt; ++jt) {
    const int jbase = jt * 32;
    __syncthreads();
    {
      const float* kr = kbase + (size_t)(jbase + srow) * D_ + sch * 8;
      s16x8 pk;
#pragma unroll
      for (int e = 0; e < 8; ++e) pk[e] = f2b(kr[e]);
      *(s16x8*)(kbuf + srow * 128 + ((sch ^ (srow & 7)) * 16)) = pk;
      const float* v1r = v1base + (size_t)(jbase + srow) * D_ + sch * 8;
      const float* v2r = v2base + (size_t)(jbase + srow) * D_ + sch * 8;
#pragma unroll
      for (int e = 0; e < 8; ++e) {
        int dd = sch * 8 + e;
        int off = dd * 64 + (((srow >> 2) ^ (dd & 7)) * 8) + (srow & 3) * 2;
        *(short*)(vtb1 + off) = f2b(v1r[e]);
        *(short*)(vtb2 + off) = f2b(v2r[e]);
      }
    }
    __syncthreads();
    if (jbase < qw + 16) {
      const unsigned cmword = cmw[jbase >> 5];
      float w[8];
#pragma unroll
      for (int sub = 0; sub < 2; ++sub) {
        const int jsb = jbase + sub * 16;
        if (jsb < qw + 16) {
          const int row = sub * 16 + r;
          s16x8 ka0 = *(const s16x8*)(kbuf + row * 128 + ((g ^ (row & 7)) * 16));
          s16x8 ka1 = *(const s16x8*)(kbuf + row * 128 + (((4 + g) ^ (row & 7)) * 16));
          f32x4 sv = {0.f, 0.f, 0.f, 0.f};
          sv = __builtin_amdgcn_mfma_f32_16x16x32_bf16(ka0, qf0, sv, 0, 0, 0);
          sv = __builtin_amdgcn_mfma_f32_16x16x32_bf16(ka1, qf1, sv, 0, 0, 0);
#pragma unroll
          for (int e = 0; e < 4; ++e) {
            int j = jsb + 4 * g + e;
            float x = 0.f;
            if (j < iq && !((cmword >> (j & 31)) & 1u)) {
              float p = __expf(sv[e] - m1) * z1i;
              x = __expf(p) - 1.f;
            }
            w[sub * 4 + e] = x;
            wsum += x;
          }
        } else {
#pragma unroll
          for (int e = 0; e < 4; ++e) w[sub * 4 + e] = 0.f;
        }
      }
      s16x8 wa;
#pragma unroll
      for (int e = 0; e < 8; ++e) wa[e] = f2b(w[e]);
#pragma unroll
      for (int db = 0; db < 4; ++db) {
        const int dd = db * 16 + r;
        const int off0 = dd * 64 + ((g ^ (dd & 7)) * 8);
        const int off1 = dd * 64 + (((4 + g) ^ (dd & 7)) * 8);
        s16x4 lo1 = *(const s16x4*)(vtb1 + off0);
        s16x4 hi1 = *(const s16x4*)(vtb1 + off1);
        s16x8 vb1 = __builtin_shufflevector(lo1, hi1, 0, 1, 2, 3, 4, 5, 6, 7);
        acc1[db] = __builtin_amdgcn_mfma_f32_16x16x32_bf16(wa, vb1, acc1[db], 0, 0, 0);
        s16x4 lo2 = *(const s16x4*)(vtb2 + off0);
        s16x4 hi2 = *(const s16x4*)(vtb2 + off1);
        s16x8 vb2 = __builtin_shufflevector(lo2, hi2, 0, 1, 2, 3, 4, 5, 6, 7);
        acc2[db] = __builtin_amdgcn_mfma_f32_16x16x32_bf16(wa, vb2, acc2[db], 0, 0, 0);
      }
    }
  }

  wsum += __shfl_xor(wsum, 16);
  wsum += __shfl_xor(wsum, 32);
  const float z2 = (float)S_ + wsum;

  float* out1 = out;
  float* out2 = out + (size_t)B_ * S_ * D_;
#pragma unroll
  for (int e = 0; e < 4; ++e) {
    float z2e = __shfl(z2, 4 * g + e);
    float inv = 1.f / z2e;
    int io = qw + 4 * g + e;
    bool zero = (io == 0);
    size_t ro = ((size_t)(b * S_) + io) * D_ + h * DK_;
#pragma unroll
    for (int db = 0; db < 4; ++db) {
      int dd = db * 16 + r;
      float c1 = vs[(size_t)b * D_ + h * DK_ + dd];
      float c2 = vs[(size_t)(B_ + b) * D_ + h * DK_ + dd];
      out1[ro + dd] = zero ? 0.f : (acc1[db][e] + c1) * inv;
      out2[ro + dd] = zero ? 0.f : (acc2[db][e] + c2) * inv;
    }
  }
}

// ============================================================================

extern "C" void kernel_launch(void* const* d_in, const int* in_sizes, int n_in,
                              void* d_out, int out_size, void* d_ws, size_t ws_size,
                              hipStream_t stream) {
  (void)in_sizes; (void)n_in; (void)out_size;
  const float* q = (const float*)d_in[0];
  const float* k = (const float*)d_in[1];
  const float* v1 = (const float*)d_in[2];
  const float* v2 = (const float*)d_in[3];
  const int* cm = (const int*)d_in[4];
  float* outp = (float*)d_out;

  const size_t VS_BYTES = 2 * B_ * D_ * sizeof(float);  // 64 KB
  const size_t FRAG_SHORTS = (size_t)BH_ * S_ * DK_;    // 8M shorts
  const size_t FRAG_BYTES = FRAG_SHORTS * 2;            // 16 MB
  const size_t NEED = VS_BYTES + 3 * FRAG_BYTES;

  float* vs = (float*)d_ws;
  (void)hipMemsetAsync(vs, 0, VS_BYTES, stream);

  if (ws_size >= NEED) {
    short* kb = (short*)((char*)d_ws + VS_BYTES);
    short* v1f = kb + FRAG_SHORTS;
    short* v2f = v1f + FRAG_SHORTS;
    prep_k<<<B_ * (S_ / 16), 256, 0, stream>>>(k, kb);
    prep_v<<<B_ * H_ * 4, 256, 0, stream>>>(v1, v2, v1f, v2f, vs);
    attn_fast6<<<1024, 256, 0, stream>>>(q, kb, v1f, v2f, cm, vs, outp);
  } else {
    vsum_kernel<<<256, 256, 0, stream>>>(v1, v2, vs);
    dualattn_fallback<<<B_ * H_ * 16, 256, 0, stream>>>(q, k, v1, v2, cm, vs, outp);
  }
}

// Round 11
// 108.899 us; speedup vs baseline: 1.6716x; 1.0820x over previous
//
#include <hip/hip_runtime.h>
#include <hip/hip_bf16.h>

#define B_ 8
#define S_ 1024
#define D_ 1024
#define H_ 16
#define DK_ 64
#define BH_ (B_ * H_)

typedef float f32x4 __attribute__((ext_vector_type(4)));
typedef short s16x8 __attribute__((ext_vector_type(8)));
typedef short s16x4 __attribute__((ext_vector_type(4)));

// hardware transcendentals: v_exp_f32 computes 2^x, v_log_f32 computes log2(x)
#define EXP2F(x) __builtin_amdgcn_exp2f(x)
#define LOG2F(x) __builtin_amdgcn_logf(x)
#define LOG2E 1.44269504088896f

// fp32 -> bf16 (RNE), manual bit version (prep kernels)
static __device__ __forceinline__ short f2b(float f) {
  unsigned u = __builtin_bit_cast(unsigned, f);
  u = u + 0x7FFFu + ((u >> 16) & 1u);
  return (short)(u >> 16);
}
// fp32 -> bf16 via intrinsic
static __device__ __forceinline__ short f2bn(float f) {
  __hip_bfloat16 h = __float2bfloat16(f);
  return __builtin_bit_cast(short, h);
}

static __device__ __forceinline__ int slotf(int g, int e) {
  return (e < 4) ? (4 * g + e) : (16 + 4 * g + (e - 4));
}

// ============================ PREP KERNELS =================================

// K f32 [b][s][d] -> bf16 [b][h][s][dk]
__global__ __launch_bounds__(256) void prep_k(const float* __restrict__ k,
                                              short* __restrict__ kb) {
  const int bid = blockIdx.x;  // 512
  const int s0 = (bid & 63) * 16;
  const int b = bid >> 6;
  const int tid = threadIdx.x;
#pragma unroll
  for (int it = 0; it < 8; ++it) {
    int li = it * 256 + tid;
    int s = s0 + (li >> 7);
    int ch = li & 127;
    int h = ch >> 3;
    int dk0 = (ch & 7) * 8;
    const float* src = k + ((size_t)(b * S_ + s)) * D_ + ch * 8;
    s16x8 o;
#pragma unroll
    for (int e = 0; e < 8; ++e) o[e] = f2b(src[e]);
    *(s16x8*)(kb + ((size_t)((b * H_ + h) * S_ + s)) * DK_ + dk0) = o;
  }
}

// V1/V2 f32 -> bf16 B-fragment layout [bh][jt32][db][lane][8] + column sums
__global__ __launch_bounds__(256) void prep_v(const float* __restrict__ v1,
                                              const float* __restrict__ v2,
                                              short* __restrict__ v1f,
                                              short* __restrict__ v2f,
                                              float* __restrict__ vs) {
  const int bid = blockIdx.x;  // 512
  const int sg = bid & 3;
  const int h = (bid >> 2) & 15;
  const int b = bid >> 6;
  const int tid = threadIdx.x;
  const int db = tid >> 6;
  const int lane = tid & 63;
  const int r = lane & 15;
  const int g = lane >> 4;
  const size_t inbase = (size_t)b * S_ * D_ + h * DK_ + db * 16 + r;
  float s1 = 0.f, s2 = 0.f;
#pragma unroll
  for (int it = 0; it < 8; ++it) {
    int jt = sg * 8 + it;
    int j0 = jt * 32;
    s16x8 o1, o2;
#pragma unroll
    for (int e = 0; e < 8; ++e) {
      int j = j0 + slotf(g, e);
      float a = v1[inbase + (size_t)j * D_];
      float c = v2[inbase + (size_t)j * D_];
      s1 += a;
      s2 += c;
      o1[e] = f2b(a);
      o2[e] = f2b(c);
    }
    size_t off = (((size_t)((b * H_ + h) * 32 + jt) * 4 + db) * 64 + lane) * 8;
    *(s16x8*)(v1f + off) = o1;
    *(s16x8*)(v2f + off) = o2;
  }
  s1 += __shfl_xor(s1, 16);
  s1 += __shfl_xor(s1, 32);
  s2 += __shfl_xor(s2, 16);
  s2 += __shfl_xor(s2, 32);
  if (g == 0) {
    int dd = db * 16 + r;
    atomicAdd(&vs[(size_t)b * D_ + h * DK_ + dd], s1);
    atomicAdd(&vs[(size_t)(B_ + b) * D_ + h * DK_ + dd], s2);
  }
}

// ============================ MAIN ATTENTION ================================
// R10 (32-wide LDS tiles, 104us): barrier-lockstep bound (~50 barriers/block,
// both pipes <50%). This round: 64-wide j-tiles -> barriers halved, 2x compute
// per sync phase; causal compares only in boundary tiles.
// 4 waves share K/V via LDS; heavy seg (8+pr) + mirror light seg (7-pr).
__global__ __launch_bounds__(256, 2) void attn_fast7(
    const float* __restrict__ q, const short* __restrict__ kb,
    const short* __restrict__ v1f, const short* __restrict__ v2f,
    const int* __restrict__ cm, const float* __restrict__ vs,
    float* __restrict__ out) {
  const int bid = blockIdx.x;   // 1024
  const int xcd = bid & 7;
  const int idx = bid >> 3;     // 0..127
  const int pr = idx & 7;
  const int bhgrp = idx >> 3;   // 0..15
  const int bh = bhgrp * 8 + xcd;
  const int b = bh >> 4, h = bh & 15;

  const int tid = threadIdx.x;
  const int wid = tid >> 6;
  const int lane = tid & 63;
  const int r = lane & 15;
  const int g = lane >> 4;

  const int aseg = 8 + pr;                    // heavy segment (64 rows)
  const int bseg = 7 - pr;                    // light segment
  const int qh = aseg * 64 + wid * 16;        // this wave's heavy col base
  const int ql = bseg * 64 + (3 - wid) * 16;  // light col base (mirrored)
  const int iqh = qh + r;
  const int iql = ql + r;
  const int njt = aseg + 1;                   // 64-wide tiles (block-uniform)

  // LDS: 2 buffers x {K 8KB (swizzled) | V1 8KB | V2 8KB}
  __shared__ __align__(16) char sbuf[2][24576];
  __shared__ unsigned cmw[32];
  {
    const int* cmb = cm + b * S_;
#pragma unroll
    for (int it = 0; it < 4; ++it) {
      unsigned long long m = __ballot(cmb[it * 256 + tid] == 1);
      if (lane == 0) {
        int w0 = it * 8 + wid * 2;
        cmw[w0] = (unsigned)m;
        cmw[w0 + 1] = (unsigned)(m >> 32);
      }
    }
  }

  // Q fragments, pre-scaled by log2e/sqrt(dk) -> scores in log2 domain
  const float qscale = 0.125f * LOG2E;
  s16x8 qfh0, qfh1, qfl0, qfl1;
  {
    const float* qp = q + ((size_t)(b * S_ + qh + r)) * D_ + h * DK_;
#pragma unroll
    for (int e = 0; e < 8; ++e) qfh0[e] = f2bn(qp[8 * g + e] * qscale);
#pragma unroll
    for (int e = 0; e < 8; ++e) qfh1[e] = f2bn(qp[32 + 8 * g + e] * qscale);
    const float* qp2 = q + ((size_t)(b * S_ + ql + r)) * D_ + h * DK_;
#pragma unroll
    for (int e = 0; e < 8; ++e) qfl0[e] = f2bn(qp2[8 * g + e] * qscale);
#pragma unroll
    for (int e = 0; e < 8; ++e) qfl1[e] = f2bn(qp2[32 + 8 * g + e] * qscale);
  }

  const short* kbh = kb + (size_t)bh * S_ * DK_;    // 4096 shorts / 64-tile
  const short* v1bh = v1f + (size_t)bh * 32 * 2048; // 4096 shorts / 64-tile
  const short* v2bh = v2f + (size_t)bh * 32 * 2048;

  const int r0s = tid >> 3, c0s = tid & 7;              // K chunk tid
  const int r1s = (tid + 256) >> 3, c1s = tid & 7;      // K chunk tid+256

// staging: thread t moves 16B chunks t and t+256 of each 8KB region
#define SLK(g0, g1, jtv)                                          \
  {                                                               \
    const short* kp = kbh + (size_t)(jtv) * 4096;                 \
    g0 = *(const s16x8*)(kp + tid * 8);                           \
    g1 = *(const s16x8*)(kp + (tid + 256) * 8);                   \
  }
#define SWK(buf, g0, g1)                                          \
  {                                                               \
    *(s16x8*)((buf) + r0s * 128 + ((c0s ^ (r0s & 7)) * 16)) = g0; \
    *(s16x8*)((buf) + r1s * 128 + ((c1s ^ (r1s & 7)) * 16)) = g1; \
  }
#define SLV(a0, a1, b0, b1, jtv)                                  \
  {                                                               \
    const short* p1 = v1bh + (size_t)(jtv) * 4096;                \
    const short* p2 = v2bh + (size_t)(jtv) * 4096;                \
    a0 = *(const s16x8*)(p1 + tid * 8);                           \
    a1 = *(const s16x8*)(p1 + (tid + 256) * 8);                   \
    b0 = *(const s16x8*)(p2 + tid * 8);                           \
    b1 = *(const s16x8*)(p2 + (tid + 256) * 8);                   \
  }
#define SWV(buf, a0, a1, b0, b1)                                  \
  {                                                               \
    *(s16x8*)((buf) + 8192 + tid * 16) = a0;                      \
    *(s16x8*)((buf) + 8192 + (tid + 256) * 16) = a1;              \
    *(s16x8*)((buf) + 16384 + tid * 16) = b0;                     \
    *(s16x8*)((buf) + 16384 + (tid + 256) * 16) = b1;             \
  }
// fragment read from swizzled K tile (row 0..63)
#define KFRAG(sK, row, quad) \
  (*(const s16x8*)((sK) + (row)*128 + (((quad) ^ ((row)&7)) * 16)))

  // ================= pass A: Z sums (log2 domain) ===========================
  float Zh = 0.f, Zl = 0.f;
  {
    s16x8 rk0, rk1;
    SLK(rk0, rk1, 0);
    __syncthreads();  // cmw ready
    SWK(sbuf[0], rk0, rk1);
    __syncthreads();
    for (int jt = 0; jt < njt; ++jt) {
      const char* sK = sbuf[jt & 1];
      const bool pf = (jt + 1 < njt);
      s16x8 nk0, nk1;
      if (pf) SLK(nk0, nk1, jt + 1);
      const bool chB = (jt == aseg);  // heavy boundary tile
      const bool clB = (jt == bseg);  // light boundary tile
#pragma unroll
      for (int sub = 0; sub < 2; ++sub) {
        const int jsb = jt * 64 + sub * 32;
        const int row0 = sub * 32 + r, row1 = row0 + 16;
        s16x8 k00 = KFRAG(sK, row0, g);
        s16x8 k01 = KFRAG(sK, row0, 4 + g);
        s16x8 k10 = KFRAG(sK, row1, g);
        s16x8 k11 = KFRAG(sK, row1, 4 + g);
        f32x4 s0 = {0.f, 0.f, 0.f, 0.f}, s1 = {0.f, 0.f, 0.f, 0.f};
        s0 = __builtin_amdgcn_mfma_f32_16x16x32_bf16(k00, qfh0, s0, 0, 0, 0);
        s0 = __builtin_amdgcn_mfma_f32_16x16x32_bf16(k01, qfh1, s0, 0, 0, 0);
        s1 = __builtin_amdgcn_mfma_f32_16x16x32_bf16(k10, qfh0, s1, 0, 0, 0);
        s1 = __builtin_amdgcn_mfma_f32_16x16x32_bf16(k11, qfh1, s1, 0, 0, 0);
        if (chB) {
#pragma unroll
          for (int e = 0; e < 4; ++e) {
            int j0 = jsb + 4 * g + e, j1 = jsb + 16 + 4 * g + e;
            Zh += (j0 < iqh) ? EXP2F(s0[e]) : 0.f;
            Zh += (j1 < iqh) ? EXP2F(s1[e]) : 0.f;
          }
        } else {
#pragma unroll
          for (int e = 0; e < 4; ++e) Zh += EXP2F(s0[e]) + EXP2F(s1[e]);
        }
        if (jsb < ql + 16) {
          f32x4 t0 = {0.f, 0.f, 0.f, 0.f}, t1 = {0.f, 0.f, 0.f, 0.f};
          t0 = __builtin_amdgcn_mfma_f32_16x16x32_bf16(k00, qfl0, t0, 0, 0, 0);
          t0 = __builtin_amdgcn_mfma_f32_16x16x32_bf16(k01, qfl1, t0, 0, 0, 0);
          t1 = __builtin_amdgcn_mfma_f32_16x16x32_bf16(k10, qfl0, t1, 0, 0, 0);
          t1 = __builtin_amdgcn_mfma_f32_16x16x32_bf16(k11, qfl1, t1, 0, 0, 0);
          if (clB) {
#pragma unroll
            for (int e = 0; e < 4; ++e) {
              int j0 = jsb + 4 * g + e, j1 = jsb + 16 + 4 * g + e;
              Zl += (j0 < iql) ? EXP2F(t0[e]) : 0.f;
              Zl += (j1 < iql) ? EXP2F(t1[e]) : 0.f;
            }
          } else {
#pragma unroll
            for (int e = 0; e < 4; ++e) Zl += EXP2F(t0[e]) + EXP2F(t1[e]);
          }
        }
      }
      if (pf) SWK(sbuf[(jt + 1) & 1], nk0, nk1);
      __syncthreads();
    }
  }
  Zh += __shfl_xor(Zh, 16);
  Zh += __shfl_xor(Zh, 32);
  Zl += __shfl_xor(Zl, 16);
  Zl += __shfl_xor(Zl, 32);
  const float lzh = -LOG2F(Zh);  // iq==0 -> Z=0 -> +inf, masked below
  const float lzl = -LOG2F(Zl);

  // ================= pass B: w = exp(p)-1, PV accumulate ====================
  f32x4 a1h[4], a2h[4], a1l[4], a2l[4];
#pragma unroll
  for (int d0 = 0; d0 < 4; ++d0) {
    a1h[d0] = (f32x4){0.f, 0.f, 0.f, 0.f};
    a2h[d0] = (f32x4){0.f, 0.f, 0.f, 0.f};
    a1l[d0] = (f32x4){0.f, 0.f, 0.f, 0.f};
    a2l[d0] = (f32x4){0.f, 0.f, 0.f, 0.f};
  }
  f32x4 wsh = {0.f, 0.f, 0.f, 0.f}, wsl = {0.f, 0.f, 0.f, 0.f};
  s16x8 ones;
#pragma unroll
  for (int e = 0; e < 8; ++e) ones[e] = (short)0x3F80;  // bf16 1.0

  {
    s16x8 rk0, rk1, ra0, ra1, rb0, rb1;
    SLK(rk0, rk1, 0);
    SLV(ra0, ra1, rb0, rb1, 0);
    SWK(sbuf[0], rk0, rk1);
    SWV(sbuf[0], ra0, ra1, rb0, rb1);
    __syncthreads();
    for (int jt = 0; jt < njt; ++jt) {
      const char* sB = sbuf[jt & 1];
      const bool pf = (jt + 1 < njt);
      s16x8 nk0, nk1, na0, na1, nb0, nb1;
      if (pf) {
        SLK(nk0, nk1, jt + 1);
        SLV(na0, na1, nb0, nb1, jt + 1);
      }
      const bool chB = (jt == aseg);
      const bool clB = (jt == bseg);
#pragma unroll
      for (int sub = 0; sub < 2; ++sub) {
        const int jsb = jt * 64 + sub * 32;
        const int row0 = sub * 32 + r, row1 = row0 + 16;
        s16x8 k00 = KFRAG(sB, row0, g);
        s16x8 k01 = KFRAG(sB, row0, 4 + g);
        s16x8 k10 = KFRAG(sB, row1, g);
        s16x8 k11 = KFRAG(sB, row1, 4 + g);
        f32x4 s0 = {0.f, 0.f, 0.f, 0.f}, s1 = {0.f, 0.f, 0.f, 0.f};
        s0 = __builtin_amdgcn_mfma_f32_16x16x32_bf16(k00, qfh0, s0, 0, 0, 0);
        s0 = __builtin_amdgcn_mfma_f32_16x16x32_bf16(k01, qfh1, s0, 0, 0, 0);
        s1 = __builtin_amdgcn_mfma_f32_16x16x32_bf16(k10, qfh0, s1, 0, 0, 0);
        s1 = __builtin_amdgcn_mfma_f32_16x16x32_bf16(k11, qfh1, s1, 0, 0, 0);
        const bool bc = (jsb < ql + 16);
        f32x4 t0, t1;
        if (bc) {
          t0 = (f32x4){0.f, 0.f, 0.f, 0.f};
          t1 = (f32x4){0.f, 0.f, 0.f, 0.f};
          t0 = __builtin_amdgcn_mfma_f32_16x16x32_bf16(k00, qfl0, t0, 0, 0, 0);
          t0 = __builtin_amdgcn_mfma_f32_16x16x32_bf16(k01, qfl1, t0, 0, 0, 0);
          t1 = __builtin_amdgcn_mfma_f32_16x16x32_bf16(k10, qfl0, t1, 0, 0, 0);
          t1 = __builtin_amdgcn_mfma_f32_16x16x32_bf16(k11, qfl1, t1, 0, 0, 0);
        }
        const unsigned cw = cmw[2 * jt + sub];
        int cmbit[8];
#pragma unroll
        for (int s2 = 0; s2 < 2; ++s2)
#pragma unroll
          for (int e = 0; e < 4; ++e)
            cmbit[s2 * 4 + e] = (int)((cw >> (s2 * 16 + 4 * g + e)) & 1u);
        // heavy weights: p = 2^(s'+lz); w = e^p-1 = 2^(p*log2e)-1
        s16x8 wah;
        {
          float wv[8];
#pragma unroll
          for (int s2 = 0; s2 < 2; ++s2) {
            f32x4 sv = s2 ? s1 : s0;
#pragma unroll
            for (int e = 0; e < 4; ++e) {
              int j = jsb + s2 * 16 + 4 * g + e;
              float pe = EXP2F(sv[e] + lzh);
              float xe = EXP2F(pe * LOG2E) - 1.f;
              bool ok = !cmbit[s2 * 4 + e];
              if (chB) ok = ok && (j < iqh);
              wv[s2 * 4 + e] = ok ? xe : 0.f;
            }
          }
#pragma unroll
          for (int e = 0; e < 8; ++e) wah[e] = f2bn(wv[e]);
        }
        s16x8 wal;
        if (bc) {
          float wv[8];
#pragma unroll
          for (int s2 = 0; s2 < 2; ++s2) {
            f32x4 sv = s2 ? t1 : t0;
#pragma unroll
            for (int e = 0; e < 4; ++e) {
              int j = jsb + s2 * 16 + 4 * g + e;
              float pe = EXP2F(sv[e] + lzl);
              float xe = EXP2F(pe * LOG2E) - 1.f;
              bool ok = !cmbit[s2 * 4 + e];
              if (clB) ok = ok && (j < iql);
              wv[s2 * 4 + e] = ok ? xe : 0.f;
            }
          }
#pragma unroll
          for (int e = 0; e < 8; ++e) wal[e] = f2bn(wv[e]);
        }
        // V fragments from LDS (linear, conflict-free)
        const char* vb1p = sB + 8192 + sub * 4096;
        const char* vb2p = sB + 16384 + sub * 4096;
        s16x8 vb1[4], vb2[4];
#pragma unroll
        for (int db = 0; db < 4; ++db) {
          vb1[db] = *(const s16x8*)(vb1p + (db * 64 + lane) * 16);
          vb2[db] = *(const s16x8*)(vb2p + (db * 64 + lane) * 16);
        }
        // PV + row-sum (ones-B) MFMAs
#pragma unroll
        for (int db = 0; db < 4; ++db) {
          a1h[db] = __builtin_amdgcn_mfma_f32_16x16x32_bf16(wah, vb1[db], a1h[db], 0, 0, 0);
          a2h[db] = __builtin_amdgcn_mfma_f32_16x16x32_bf16(wah, vb2[db], a2h[db], 0, 0, 0);
        }
        wsh = __builtin_amdgcn_mfma_f32_16x16x32_bf16(wah, ones, wsh, 0, 0, 0);
        if (bc) {
#pragma unroll
          for (int db = 0; db < 4; ++db) {
            a1l[db] = __builtin_amdgcn_mfma_f32_16x16x32_bf16(wal, vb1[db], a1l[db], 0, 0, 0);
            a2l[db] = __builtin_amdgcn_mfma_f32_16x16x32_bf16(wal, vb2[db], a2l[db], 0, 0, 0);
          }
          wsl = __builtin_amdgcn_mfma_f32_16x16x32_bf16(wal, ones, wsl, 0, 0, 0);
        }
      }
      if (pf) {
        SWK(sbuf[(jt + 1) & 1], nk0, nk1);
        SWV(sbuf[(jt + 1) & 1], na0, na1, nb0, nb1);
      }
      __syncthreads();
    }
  }
#undef SLK
#undef SLV
#undef SWK
#undef SWV
#undef KFRAG

  float* out1 = out;
  float* out2 = out + (size_t)B_ * S_ * D_;
  const float* vs1 = vs + (size_t)b * D_ + h * DK_;
  const float* vs2 = vs + (size_t)(B_ + b) * D_ + h * DK_;

#pragma unroll
  for (int e = 0; e < 4; ++e) {
    // heavy col (wsh[e] = row-sum for q row 4g+e; matches acc row layout)
    {
      float inv = 1.f / ((float)S_ + wsh[e]);
      int io = qh + 4 * g + e;
      size_t ro = ((size_t)(b * S_) + io) * D_ + h * DK_;
#pragma unroll
      for (int db = 0; db < 4; ++db) {
        int dd = db * 16 + r;
        out1[ro + dd] = (a1h[db][e] + vs1[dd]) * inv;
        out2[ro + dd] = (a2h[db][e] + vs2[dd]) * inv;
      }
    }
    // light col
    {
      float inv = 1.f / ((float)S_ + wsl[e]);
      int io = ql + 4 * g + e;
      bool zero = (io == 0);  // reference zeroes p row 0
      size_t ro = ((size_t)(b * S_) + io) * D_ + h * DK_;
#pragma unroll
      for (int db = 0; db < 4; ++db) {
        int dd = db * 16 + r;
        out1[ro + dd] = zero ? 0.f : (a1l[db][e] + vs1[dd]) * inv;
        out2[ro + dd] = zero ? 0.f : (a2l[db][e] + vs2[dd]) * inv;
      }
    }
  }
}

// ====================== FALLBACK (needs only 64KB ws) =======================

__global__ __launch_bounds__(256) void vsum_kernel(const float* __restrict__ v1,
                                                   const float* __restrict__ v2,
                                                   float* __restrict__ vs) {
  int bid = blockIdx.x;
  int sc = bid & 7, dc = (bid >> 3) & 3, b = bid >> 5;
  int d = dc * 256 + threadIdx.x;
  const float* p1 = v1 + ((size_t)b * S_ + sc * 128) * D_ + d;
  const float* p2 = v2 + ((size_t)b * S_ + sc * 128) * D_ + d;
  float s1 = 0.f, s2 = 0.f;
  for (int j = 0; j < 128; ++j) {
    s1 += p1[(size_t)j * D_];
    s2 += p2[(size_t)j * D_];
  }
  atomicAdd(&vs[b * D_ + d], s1);
  atomicAdd(&vs[B_ * D_ + b * D_ + d], s2);
}

__global__ __launch_bounds__(256) void dualattn_fallback(
    const float* __restrict__ q, const float* __restrict__ k,
    const float* __restrict__ v1, const float* __restrict__ v2,
    const int* __restrict__ cm, const float* __restrict__ vs,
    float* __restrict__ out) {
  const int bid = blockIdx.x;
  const int qt = bid & 15;
  const int h = (bid >> 4) & 15;
  const int b = bid >> 8;
  const int tid = threadIdx.x;
  const int wid = tid >> 6;
  const int lane = tid & 63;
  const int r = lane & 15;
  const int g = lane >> 4;
  const int qw = qt * 64 + wid * 16;
  const int iq = qw + r;

  __shared__ __align__(16) char kbuf[32 * 128];
  __shared__ __align__(16) char vtb1[64 * 64];
  __shared__ __align__(16) char vtb2[64 * 64];
  __shared__ unsigned cmw[32];

  {
    const int* cmb = cm + b * S_;
#pragma unroll
    for (int it = 0; it < 4; ++it) {
      int c = cmb[it * 256 + tid];
      unsigned long long m = __ballot(c == 1);
      if (lane == 0) {
        int w0 = (it * 256 + wid * 64) >> 5;
        cmw[w0] = (unsigned)m;
        cmw[w0 + 1] = (unsigned)(m >> 32);
      }
    }
  }

  s16x8 qf0, qf1;
  {
    const float* qp = q + ((size_t)(b * S_) + qw + r) * D_ + h * DK_;
#pragma unroll
    for (int e = 0; e < 8; ++e) qf0[e] = f2b(qp[8 * g + e] * 0.125f);
#pragma unroll
    for (int e = 0; e < 8; ++e) qf1[e] = f2b(qp[32 + 8 * g + e] * 0.125f);
  }

  const int njt = 2 * qt + 2;
  const float* kbase = k + (size_t)(b * S_) * D_ + h * DK_;
  const float* v1base = v1 + (size_t)(b * S_) * D_ + h * DK_;
  const float* v2base = v2 + (size_t)(b * S_) * D_ + h * DK_;
  const int srow = tid >> 3;
  const int sch = tid & 7;

  float m1 = -INFINITY, Z1 = 0.f;
  for (int jt = 0; jt < njt; ++jt) {
    const int jbase = jt * 32;
    __syncthreads();
    {
      const float* kr = kbase + (size_t)(jbase + srow) * D_ + sch * 8;
      s16x8 pk;
#pragma unroll
      for (int e = 0; e < 8; ++e) pk[e] = f2b(kr[e]);
      *(s16x8*)(kbuf + srow * 128 + ((sch ^ (srow & 7)) * 16)) = pk;
    }
    __syncthreads();
    if (jbase < qw + 16) {
#pragma unroll
      for (int sub = 0; sub < 2; ++sub) {
        const int jsb = jbase + sub * 16;
        if (jsb < qw + 16) {
          const int row = sub * 16 + r;
          s16x8 ka0 = *(const s16x8*)(kbuf + row * 128 + ((g ^ (row & 7)) * 16));
          s16x8 ka1 = *(const s16x8*)(kbuf + row * 128 + (((4 + g) ^ (row & 7)) * 16));
          f32x4 sv = {0.f, 0.f, 0.f, 0.f};
          sv = __builtin_amdgcn_mfma_f32_16x16x32_bf16(ka0, qf0, sv, 0, 0, 0);
          sv = __builtin_amdgcn_mfma_f32_16x16x32_bf16(ka1, qf1, sv, 0, 0, 0);
          float tm = m1;
#pragma unroll
          for (int e = 0; e < 4; ++e) {
            int j = jsb + 4 * g + e;
            if (j < iq) tm = fmaxf(tm, sv[e]);
          }
          if (tm > m1) { Z1 *= __expf(m1 - tm); m1 = tm; }
#pragma unroll
          for (int e = 0; e < 4; ++e) {
            int j = jsb + 4 * g + e;
            if (j < iq) Z1 += __expf(sv[e] - tm);
          }
        }
      }
    }
  }
#pragma unroll
  for (int off = 16; off < 64; off <<= 1) {
    float mo = __shfl_xor(m1, off);
    float zo = __shfl_xor(Z1, off);
    float mn = fmaxf(m1, mo);
    if (mn > -INFINITY) {
      Z1 = Z1 * __expf(m1 - mn) + zo * __expf(mo - mn);
      m1 = mn;
    }
  }
  float z1i;
  if (m1 > -INFINITY) { z1i = 1.f / Z1; }
  else { z1i = 0.f; m1 = 0.f; }

  f32x4 acc1[4], acc2[4];
#pragma unroll
  for (int d0 = 0; d0 < 4; ++d0) {
    acc1[d0] = (f32x4){0.f, 0.f, 0.f, 0.f};
    acc2[d0] = (f32x4){0.f, 0.f, 0.f, 0.f};
  }
  float wsum = 0.f;

  for (int jt = 0; jt < njt; ++jt) {
    const int jbase = jt * 32;
    __syncthreads();
    {
      const float* kr = kbase + (size_t)(jbase + srow) * D_ + sch * 8;
      s16x8 pk;
#pragma unroll
      for (int e = 0; e < 8; ++e) pk[e] = f2b(kr[e]);
      *(s16x8*)(kbuf + srow * 128 + ((sch ^ (srow & 7)) * 16)) = pk;
      const float* v1r = v1base + (size_t)(jbase + srow) * D_ + sch * 8;
      const float* v2r = v2base + (size_t)(jbase + srow) * D_ + sch * 8;
#pragma unroll
      for (int e = 0; e < 8; ++e) {
        int dd = sch * 8 + e;
        int off = dd * 64 + (((srow >> 2) ^ (dd & 7)) * 8) + (srow & 3) * 2;
        *(short*)(vtb1 + off) = f2b(v1r[e]);
        *(short*)(vtb2 + off) = f2b(v2r[e]);
      }
    }
    __syncthreads();
    if (jbase < qw + 16) {
      const unsigned cmword = cmw[jbase >> 5];
      float w[8];
#pragma unroll
      for (int sub = 0; sub < 2; ++sub) {
        const int jsb = jbase + sub * 16;
        if (jsb < qw + 16) {
          const int row = sub * 16 + r;
          s16x8 ka0 = *(const s16x8*)(kbuf + row * 128 + ((g ^ (row & 7)) * 16));
          s16x8 ka1 = *(const s16x8*)(kbuf + row * 128 + (((4 + g) ^ (row & 7)) * 16));
          f32x4 sv = {0.f, 0.f, 0.f, 0.f};
          sv = __builtin_amdgcn_mfma_f32_16x16x32_bf16(ka0, qf0, sv, 0, 0, 0);
          sv = __builtin_amdgcn_mfma_f32_16x16x32_bf16(ka1, qf1, sv, 0, 0, 0);
#pragma unroll
          for (int e = 0; e < 4; ++e) {
            int j = jsb + 4 * g + e;
            float x = 0.f;
            if (j < iq && !((cmword >> (j & 31)) & 1u)) {
              float p = __expf(sv[e] - m1) * z1i;
              x = __expf(p) - 1.f;
            }
            w[sub * 4 + e] = x;
            wsum += x;
          }
        } else {
#pragma unroll
          for (int e = 0; e < 4; ++e) w[sub * 4 + e] = 0.f;
        }
      }
      s16x8 wa;
#pragma unroll
      for (int e = 0; e < 8; ++e) wa[e] = f2b(w[e]);
#pragma unroll
      for (int db = 0; db < 4; ++db) {
        const int dd = db * 16 + r;
        const int off0 = dd * 64 + ((g ^ (dd & 7)) * 8);
        const int off1 = dd * 64 + (((4 + g) ^ (dd & 7)) * 8);
        s16x4 lo1 = *(const s16x4*)(vtb1 + off0);
        s16x4 hi1 = *(const s16x4*)(vtb1 + off1);
        s16x8 vb1 = __builtin_shufflevector(lo1, hi1, 0, 1, 2, 3, 4, 5, 6, 7);
        acc1[db] = __builtin_amdgcn_mfma_f32_16x16x32_bf16(wa, vb1, acc1[db], 0, 0, 0);
        s16x4 lo2 = *(const s16x4*)(vtb2 + off0);
        s16x4 hi2 = *(const s16x4*)(vtb2 + off1);
        s16x8 vb2 = __builtin_shufflevector(lo2, hi2, 0, 1, 2, 3, 4, 5, 6, 7);
        acc2[db] = __builtin_amdgcn_mfma_f32_16x16x32_bf16(wa, vb2, acc2[db], 0, 0, 0);
      }
    }
  }

  wsum += __shfl_xor(wsum, 16);
  wsum += __shfl_xor(wsum, 32);
  const float z2 = (float)S_ + wsum;

  float* out1 = out;
  float* out2 = out + (size_t)B_ * S_ * D_;
#pragma unroll
  for (int e = 0; e < 4; ++e) {
    float z2e = __shfl(z2, 4 * g + e);
    float inv = 1.f / z2e;
    int io = qw + 4 * g + e;
    bool zero = (io == 0);
    size_t ro = ((size_t)(b * S_) + io) * D_ + h * DK_;
#pragma unroll
    for (int db = 0; db < 4; ++db) {
      int dd = db * 16 + r;
      float c1 = vs[(size_t)b * D_ + h * DK_ + dd];
      float c2 = vs[(size_t)(B_ + b) * D_ + h * DK_ + dd];
      out1[ro + dd] = zero ? 0.f : (acc1[db][e] + c1) * inv;
      out2[ro + dd] = zero ? 0.f : (acc2[db][e] + c2) * inv;
    }
  }
}

// ============================================================================

extern "C" void kernel_launch(void* const* d_in, const int* in_sizes, int n_in,
                              void* d_out, int out_size, void* d_ws, size_t ws_size,
                              hipStream_t stream) {
  (void)in_sizes; (void)n_in; (void)out_size;
  const float* q = (const float*)d_in[0];
  const float* k = (const float*)d_in[1];
  const float* v1 = (const float*)d_in[2];
  const float* v2 = (const float*)d_in[3];
  const int* cm = (const int*)d_in[4];
  float* outp = (float*)d_out;

  const size_t VS_BYTES = 2 * B_ * D_ * sizeof(float);  // 64 KB
  const size_t FRAG_SHORTS = (size_t)BH_ * S_ * DK_;    // 8M shorts
  const size_t FRAG_BYTES = FRAG_SHORTS * 2;            // 16 MB
  const size_t NEED = VS_BYTES + 3 * FRAG_BYTES;

  float* vs = (float*)d_ws;
  (void)hipMemsetAsync(vs, 0, VS_BYTES, stream);

  if (ws_size >= NEED) {
    short* kb = (short*)((char*)d_ws + VS_BYTES);
    short* v1f = kb + FRAG_SHORTS;
    short* v2f = v1f + FRAG_SHORTS;
    prep_k<<<B_ * (S_ / 16), 256, 0, stream>>>(k, kb);
    prep_v<<<B_ * H_ * 4, 256, 0, stream>>>(v1, v2, v1f, v2f, vs);
    attn_fast7<<<1024, 256, 0, stream>>>(q, kb, v1f, v2f, cm, vs, outp);
  } else {
    vsum_kernel<<<256, 256, 0, stream>>>(v1, v2, vs);
    dualattn_fallback<<<B_ * H_ * 16, 256, 0, stream>>>(q, k, v1, v2, cm, vs, outp);
  }
}